// Round 1
// baseline (278.967 us; speedup 1.0000x reference)
//
#include <hip/hip_runtime.h>
#include <hip/hip_fp16.h>

typedef float f32x4 __attribute__((ext_vector_type(4)));
typedef __bf16 bf16x8 __attribute__((ext_vector_type(8)));

#define CDIM 128
#define HW 256

static __device__ __forceinline__ unsigned short f2bf(float f) {
    unsigned u = __builtin_bit_cast(unsigned, f);
    u += 0x7FFFu + ((u >> 16) & 1u);
    return (unsigned short)(u >> 16);
}

static __device__ __forceinline__ float2 ldh2(const unsigned short* p) {
    __half2 h = *reinterpret_cast<const __half2*>(p);
    return __half22float2(h);
}

// ---- kernel 1: transpose plane (C,H,W) f32 -> (H,W,C) f16 ----
__global__ __launch_bounds__(256) void k_transpose(const float* __restrict__ plane,
                                                   unsigned short* __restrict__ planeT) {
    __shared__ unsigned short tile[32][130];
    int tid = threadIdx.x;
    int y  = blockIdx.x >> 3;
    int x0 = (blockIdx.x & 7) * 32;
    int tx = tid & 31, tc = tid >> 5;
    for (int cc = 0; cc < 128; cc += 8) {
        int c = cc + tc;
        float v = plane[c * (HW * HW) + y * HW + x0 + tx];
        tile[tx][c] = __half_as_ushort(__float2half(v));
    }
    __syncthreads();
    for (int it = 0; it < 16; ++it) {
        int idx = it * 256 + tid;
        int c = idx & 127, xi = idx >> 7;
        planeT[(y * HW + x0 + xi) * CDIM + c] = tile[xi][c];
    }
}

// ---- kernel 2: convert W1,W2 f32 -> bf16 (same row-major layout) ----
__global__ __launch_bounds__(256) void k_wconv(const float* __restrict__ W1,
                                               const float* __restrict__ W2,
                                               unsigned short* __restrict__ W1b,
                                               unsigned short* __restrict__ W2b) {
    int i = blockIdx.x * 256 + threadIdx.x;
    if (i < 16384) W1b[i] = f2bf(W1[i]);
    else           W2b[i - 16384] = f2bf(W2[i - 16384]);
}

// ---- kernel 3: fused sample + MLP ----
// block = 128 threads = 2 independent waves; each wave owns 16 points.
__global__ __launch_bounds__(128) void k_main(const float* __restrict__ coords,
                                              const unsigned short* __restrict__ planeT,
                                              const unsigned short* __restrict__ W1b,
                                              const unsigned short* __restrict__ W2b,
                                              const float* __restrict__ b1,
                                              const float* __restrict__ b2,
                                              const float* __restrict__ W3,
                                              const float* __restrict__ b3,
                                              float* __restrict__ out, int N) {
    __shared__ alignas(16) unsigned short feat[32][136];
    __shared__ alignas(16) unsigned short h1s[32][136];

    const int tid  = threadIdx.x;
    const int wave = tid >> 6, lane = tid & 63;
    const int ro   = wave * 16;
    const int pbase = blockIdx.x * 32 + ro;
    const int l32 = lane & 31, half = lane >> 5;

    // ---------------- phase A: bilinear sampling -> features (bf16 in LDS) --------
#pragma unroll 2
    for (int it = 0; it < 8; ++it) {
        int pl = it * 2 + half;            // local point 0..15
        int p  = pbase + pl;
        if (p >= N) p = N - 1;
        float gx = coords[p * 3 + 0];
        float gy = coords[p * 3 + 1];
        float gz = coords[p * 3 + 2];
        float ix = (gx + 1.f) * 127.5f;
        float iy = (gy + 1.f) * 127.5f;
        float iz = (gz + 1.f) * 127.5f;
        float xf = floorf(ix), yf = floorf(iy), zf = floorf(iz);
        float wx1 = ix - xf, wy1 = iy - yf, wz1 = iz - zf;
        float wx0 = 1.f - wx1, wy0 = 1.f - wy1, wz0 = 1.f - wz1;
        int x0i = (int)xf, y0i = (int)yf, z0i = (int)zf;
        x0i = max(0, min(x0i, HW - 1));
        y0i = max(0, min(y0i, HW - 1));
        z0i = max(0, min(z0i, HW - 1));
        int x1i = min(x0i + 1, HW - 1);
        int y1i = min(y0i + 1, HW - 1);
        int z1i = min(z0i + 1, HW - 1);

        int ox0 = x0i * CDIM, ox1 = x1i * CDIM;
        int ry0 = y0i << 15, ry1 = y1i << 15;
        int rz0 = z0i << 15, rz1 = z1i << 15;

        const unsigned short* a00 = planeT + ry0 + ox0;
        const unsigned short* a01 = planeT + ry0 + ox1;
        const unsigned short* a10 = planeT + ry1 + ox0;
        const unsigned short* a11 = planeT + ry1 + ox1;
        const unsigned short* c00 = planeT + rz0 + ox0;
        const unsigned short* c01 = planeT + rz0 + ox1;
        const unsigned short* c10 = planeT + rz1 + ox0;
        const unsigned short* c11 = planeT + rz1 + ox1;

#pragma unroll
        for (int chh = 0; chh < 2; ++chh) {
            int c = l32 * 2 + chh * 64;
            float2 va00 = ldh2(a00 + c), va01 = ldh2(a01 + c);
            float2 va10 = ldh2(a10 + c), va11 = ldh2(a11 + c);
            float2 vc00 = ldh2(c00 + c), vc01 = ldh2(c01 + c);
            float2 vc10 = ldh2(c10 + c), vc11 = ldh2(c11 + c);
            float xy0 = wy0 * (wx0 * va00.x + wx1 * va01.x) + wy1 * (wx0 * va10.x + wx1 * va11.x);
            float xy1 = wy0 * (wx0 * va00.y + wx1 * va01.y) + wy1 * (wx0 * va10.y + wx1 * va11.y);
            float xz0 = wz0 * (wx0 * vc00.x + wx1 * vc01.x) + wz1 * (wx0 * vc10.x + wx1 * vc11.x);
            float xz1 = wz0 * (wx0 * vc00.y + wx1 * vc01.y) + wz1 * (wx0 * vc10.y + wx1 * vc11.y);
            float f0 = xy0 * xz0 * xz0;
            float f1 = xy1 * xz1 * xz1;
            unsigned pack = (unsigned)f2bf(f0) | ((unsigned)f2bf(f1) << 16);
            *reinterpret_cast<unsigned*>(&feat[ro + pl][c]) = pack;
        }
    }

    // ---------------- GEMM1: h1 = sin(30*(feat @ W1^T + b1)) ---------------------
    const int j = lane & 15, rg = lane >> 4;
    f32x4 acc[8];
#pragma unroll
    for (int nt = 0; nt < 8; ++nt) acc[nt] = (f32x4){0.f, 0.f, 0.f, 0.f};

#pragma unroll
    for (int kk = 0; kk < 4; ++kk) {
        const uint4* ap = reinterpret_cast<const uint4*>(&feat[ro + j][kk * 32 + rg * 8]);
        bf16x8 a = __builtin_bit_cast(bf16x8, *ap);
#pragma unroll
        for (int nt = 0; nt < 8; ++nt) {
            const uint4* bp = reinterpret_cast<const uint4*>(W1b + (nt * 16 + j) * 128 + kk * 32 + rg * 8);
            bf16x8 b = __builtin_bit_cast(bf16x8, *bp);
            acc[nt] = __builtin_amdgcn_mfma_f32_16x16x32_bf16(a, b, acc[nt], 0, 0, 0);
        }
    }

#pragma unroll
    for (int nt = 0; nt < 8; ++nt) {
        float bb = b1[nt * 16 + j];
#pragma unroll
        for (int r = 0; r < 4; ++r) {
            float h = __sinf(30.f * (acc[nt][r] + bb));
            h1s[ro + rg * 4 + r][nt * 16 + j] = f2bf(h);
        }
    }

    // ---------------- GEMM2: h2 = sin(30*(h1 @ W2^T + b2)) -----------------------
    f32x4 acc2[8];
#pragma unroll
    for (int nt = 0; nt < 8; ++nt) acc2[nt] = (f32x4){0.f, 0.f, 0.f, 0.f};

#pragma unroll
    for (int kk = 0; kk < 4; ++kk) {
        const uint4* ap = reinterpret_cast<const uint4*>(&h1s[ro + j][kk * 32 + rg * 8]);
        bf16x8 a = __builtin_bit_cast(bf16x8, *ap);
#pragma unroll
        for (int nt = 0; nt < 8; ++nt) {
            const uint4* bp = reinterpret_cast<const uint4*>(W2b + (nt * 16 + j) * 128 + kk * 32 + rg * 8);
            bf16x8 b = __builtin_bit_cast(bf16x8, *bp);
            acc2[nt] = __builtin_amdgcn_mfma_f32_16x16x32_bf16(a, b, acc2[nt], 0, 0, 0);
        }
    }

    // ---------------- epilogue: out = h2 @ W3^T + b3 ------------------------------
    float part[4] = {0.f, 0.f, 0.f, 0.f};
#pragma unroll
    for (int nt = 0; nt < 8; ++nt) {
        float bb = b2[nt * 16 + j];
        float w3 = W3[nt * 16 + j];
#pragma unroll
        for (int r = 0; r < 4; ++r)
            part[r] += __sinf(30.f * (acc2[nt][r] + bb)) * w3;
    }
#pragma unroll
    for (int off = 1; off < 16; off <<= 1) {
#pragma unroll
        for (int r = 0; r < 4; ++r) part[r] += __shfl_xor(part[r], off, 64);
    }
    if (j == 0) {
        float bb3 = b3[0];
#pragma unroll
        for (int r = 0; r < 4; ++r) {
            int p = pbase + rg * 4 + r;
            if (p < N) out[p] = part[r] + bb3;
        }
    }
}

extern "C" void kernel_launch(void* const* d_in, const int* in_sizes, int n_in,
                              void* d_out, int out_size, void* d_ws, size_t ws_size,
                              hipStream_t stream) {
    const float* coords = (const float*)d_in[0];
    const float* plane  = (const float*)d_in[1];
    const float* W1     = (const float*)d_in[4];
    const float* b1     = (const float*)d_in[5];
    const float* W2     = (const float*)d_in[6];
    const float* b2     = (const float*)d_in[7];
    const float* W3     = (const float*)d_in[8];
    const float* b3     = (const float*)d_in[9];
    float* out = (float*)d_out;
    int N = in_sizes[0] / 3;

    unsigned short* planeT = (unsigned short*)d_ws;                       // 16 MB
    unsigned short* W1b = (unsigned short*)((char*)d_ws + 16777216);      // 32 KB
    unsigned short* W2b = (unsigned short*)((char*)d_ws + 16777216 + 32768);

    k_transpose<<<dim3(HW * 8), dim3(256), 0, stream>>>(plane, planeT);
    k_wconv<<<dim3(128), dim3(256), 0, stream>>>(W1, W2, W1b, W2b);
    k_main<<<dim3((N + 31) / 32), dim3(128), 0, stream>>>(coords, planeT, W1b, W2b,
                                                          b1, b2, W3, b3, out, N);
}

// Round 4
// 278.632 us; speedup vs baseline: 1.0012x; 1.0012x over previous
//
#include <hip/hip_runtime.h>
#include <hip/hip_fp16.h>

typedef float f32x4 __attribute__((ext_vector_type(4)));
typedef __bf16 bf16x8 __attribute__((ext_vector_type(8)));

#define CDIM 128
#define HW 256

static __device__ __forceinline__ unsigned short f2bf(float f) {
    unsigned u = __builtin_bit_cast(unsigned, f);
    u += 0x7FFFu + ((u >> 16) & 1u);
    return (unsigned short)(u >> 16);
}

// ---- kernel 1: transpose plane (C,H,W) f32 -> (H,W,C) f16 ----
__global__ __launch_bounds__(256) void k_transpose(const float* __restrict__ plane,
                                                   unsigned short* __restrict__ planeT) {
    __shared__ unsigned short tile[32][130];
    int tid = threadIdx.x;
    int y  = blockIdx.x >> 3;
    int x0 = (blockIdx.x & 7) * 32;
    int tx = tid & 31, tc = tid >> 5;
    for (int cc = 0; cc < 128; cc += 8) {
        int c = cc + tc;
        float v = plane[c * (HW * HW) + y * HW + x0 + tx];
        tile[tx][c] = __half_as_ushort(__float2half(v));
    }
    __syncthreads();
    for (int it = 0; it < 16; ++it) {
        int idx = it * 256 + tid;
        int c = idx & 127, xi = idx >> 7;
        planeT[(y * HW + x0 + xi) * CDIM + c] = tile[xi][c];
    }
}

// ---- kernel 2: convert W1,W2 f32 -> bf16 (row-major kept) ----
__global__ __launch_bounds__(256) void k_wconv(const float* __restrict__ W1,
                                               const float* __restrict__ W2,
                                               unsigned short* __restrict__ W1b,
                                               unsigned short* __restrict__ W2b) {
    int i = blockIdx.x * 256 + threadIdx.x;
    if (i < 16384) W1b[i] = f2bf(W1[i]);
    else           W2b[i - 16384] = f2bf(W2[i - 16384]);
}

// ---- gather helpers ----
struct PrepT {
    int off[8];     // element offsets of the 8 corner rows (incl. lane ch-group)
    float w[8];     // xy weights [0..3] = w00,w01,w10,w11; xz weights [4..7]
};

__device__ __forceinline__ PrepT prep(const float* __restrict__ coords, int p, int cg) {
    PrepT r;
    float gx = coords[p * 3 + 0];
    float gy = coords[p * 3 + 1];
    float gz = coords[p * 3 + 2];
    float ix = (gx + 1.f) * 127.5f;
    float iy = (gy + 1.f) * 127.5f;
    float iz = (gz + 1.f) * 127.5f;
    float xf = floorf(ix), yf = floorf(iy), zf = floorf(iz);
    float wx1 = ix - xf, wy1 = iy - yf, wz1 = iz - zf;
    float wx0 = 1.f - wx1, wy0 = 1.f - wy1, wz0 = 1.f - wz1;
    int x0 = max(0, min((int)xf, HW - 1));
    int y0 = max(0, min((int)yf, HW - 1));
    int z0 = max(0, min((int)zf, HW - 1));
    int x1 = min(x0 + 1, HW - 1);
    int y1 = min(y0 + 1, HW - 1);
    int z1 = min(z0 + 1, HW - 1);
    int cx0 = x0 * CDIM + cg * 8, cx1 = x1 * CDIM + cg * 8;
    r.off[0] = (y0 << 15) + cx0; r.off[1] = (y0 << 15) + cx1;
    r.off[2] = (y1 << 15) + cx0; r.off[3] = (y1 << 15) + cx1;
    r.off[4] = (z0 << 15) + cx0; r.off[5] = (z0 << 15) + cx1;
    r.off[6] = (z1 << 15) + cx0; r.off[7] = (z1 << 15) + cx1;
    r.w[0] = wy0 * wx0; r.w[1] = wy0 * wx1; r.w[2] = wy1 * wx0; r.w[3] = wy1 * wx1;
    r.w[4] = wz0 * wx0; r.w[5] = wz0 * wx1; r.w[6] = wz1 * wx0; r.w[7] = wz1 * wx1;
    return r;
}

struct LdT { uint4 d[8]; };

__device__ __forceinline__ LdT ld8(const unsigned short* __restrict__ planeT, const PrepT& a) {
    LdT r;
#pragma unroll
    for (int c = 0; c < 8; ++c)
        r.d[c] = *reinterpret_cast<const uint4*>(planeT + a.off[c]);
    return r;
}

__device__ __forceinline__ void interp_store(unsigned short* dst, const PrepT& a, const LdT& L) {
    unsigned o[4];
#pragma unroll
    for (int g = 0; g < 4; ++g) {
        float2 v[8];
#pragma unroll
        for (int c = 0; c < 8; ++c) {
            unsigned wrd = reinterpret_cast<const unsigned*>(&L.d[c])[g];
            v[c] = __half22float2(__builtin_bit_cast(__half2, wrd));
        }
        float xy0 = a.w[0] * v[0].x + a.w[1] * v[1].x + a.w[2] * v[2].x + a.w[3] * v[3].x;
        float xy1 = a.w[0] * v[0].y + a.w[1] * v[1].y + a.w[2] * v[2].y + a.w[3] * v[3].y;
        float xz0 = a.w[4] * v[4].x + a.w[5] * v[5].x + a.w[6] * v[6].x + a.w[7] * v[7].x;
        float xz1 = a.w[4] * v[4].y + a.w[5] * v[5].y + a.w[6] * v[6].y + a.w[7] * v[7].y;
        float f0 = xy0 * xz0 * xz0;
        float f1 = xy1 * xz1 * xz1;
        o[g] = (unsigned)f2bf(f0) | ((unsigned)f2bf(f1) << 16);
    }
    uint4 pack; pack.x = o[0]; pack.y = o[1]; pack.z = o[2]; pack.w = o[3];
    *reinterpret_cast<uint4*>(dst) = pack;
}

// ---- kernel 3: fused sample + MLP ----
// block = 128 threads = 2 independent waves; each wave owns 16 points.
// __syncthreads() between each LDS-producer phase and its consumer: the LDS
// writes and reads go through different pointer types (ushort/unsigned vs
// uint4); without an explicit fence the scheduler may hoist ds_reads above
// the ds_writes (TBAA no-alias) — suspected cause of R2/R3 corruption.
__global__ __launch_bounds__(128) void k_main(const float* __restrict__ coords,
                                              const unsigned short* __restrict__ planeT,
                                              const unsigned short* __restrict__ W1b,
                                              const unsigned short* __restrict__ W2b,
                                              const float* __restrict__ b1,
                                              const float* __restrict__ b2,
                                              const float* __restrict__ W3,
                                              const float* __restrict__ b3,
                                              float* __restrict__ out, int N) {
    __shared__ alignas(16) unsigned short feat[32][136];
    __shared__ alignas(16) unsigned short h1s[32][136];

    const int tid  = threadIdx.x;
    const int wave = tid >> 6, lane = tid & 63;
    const int ro   = wave * 16;
    const int pbase = blockIdx.x * 32 + ro;

    // -------- phase A: bilinear sampling, 4 points/iter, depth-2 pipeline --------
    {
        const int pt = lane >> 4, cg = lane & 15;
        int p0 = min(pbase + 0 * 4 + pt, N - 1);
        int p1 = min(pbase + 1 * 4 + pt, N - 1);
        int p2 = min(pbase + 2 * 4 + pt, N - 1);
        int p3 = min(pbase + 3 * 4 + pt, N - 1);
        PrepT a0 = prep(coords, p0, cg);
        LdT   d0 = ld8(planeT, a0);
        PrepT a1 = prep(coords, p1, cg);
        LdT   d1 = ld8(planeT, a1);
        interp_store(&feat[ro + 0 * 4 + pt][cg * 8], a0, d0);
        PrepT a2 = prep(coords, p2, cg);
        LdT   d2 = ld8(planeT, a2);
        interp_store(&feat[ro + 1 * 4 + pt][cg * 8], a1, d1);
        PrepT a3 = prep(coords, p3, cg);
        LdT   d3 = ld8(planeT, a3);
        interp_store(&feat[ro + 2 * 4 + pt][cg * 8], a2, d2);
        interp_store(&feat[ro + 3 * 4 + pt][cg * 8], a3, d3);
    }

    __syncthreads();   // order feat ds_writes before GEMM1 ds_reads

    // -------- GEMM1: h1 = sin(30*(feat @ W1^T + b1)) --------
    const int j = lane & 15, rg = lane >> 4;
    f32x4 acc[8];
#pragma unroll
    for (int nt = 0; nt < 8; ++nt) acc[nt] = (f32x4){0.f, 0.f, 0.f, 0.f};

#pragma unroll
    for (int kk = 0; kk < 4; ++kk) {
        bf16x8 a = __builtin_bit_cast(bf16x8, *reinterpret_cast<const uint4*>(&feat[ro + j][kk * 32 + rg * 8]));
#pragma unroll
        for (int nt = 0; nt < 8; ++nt) {
            bf16x8 b = __builtin_bit_cast(bf16x8, *reinterpret_cast<const uint4*>(W1b + (nt * 16 + j) * 128 + kk * 32 + rg * 8));
            acc[nt] = __builtin_amdgcn_mfma_f32_16x16x32_bf16(a, b, acc[nt], 0, 0, 0);
        }
    }

#pragma unroll
    for (int nt = 0; nt < 8; ++nt) {
        float bb = b1[nt * 16 + j];
#pragma unroll
        for (int r = 0; r < 4; ++r) {
            float h = __sinf(30.f * (acc[nt][r] + bb));
            h1s[ro + rg * 4 + r][nt * 16 + j] = f2bf(h);
        }
    }

    __syncthreads();   // order h1s ds_writes before GEMM2 ds_reads

    // -------- GEMM2: h2 = sin(30*(h1 @ W2^T + b2)) --------
    f32x4 acc2[8];
#pragma unroll
    for (int nt = 0; nt < 8; ++nt) acc2[nt] = (f32x4){0.f, 0.f, 0.f, 0.f};

#pragma unroll
    for (int kk = 0; kk < 4; ++kk) {
        bf16x8 a = __builtin_bit_cast(bf16x8, *reinterpret_cast<const uint4*>(&h1s[ro + j][kk * 32 + rg * 8]));
#pragma unroll
        for (int nt = 0; nt < 8; ++nt) {
            bf16x8 b = __builtin_bit_cast(bf16x8, *reinterpret_cast<const uint4*>(W2b + (nt * 16 + j) * 128 + kk * 32 + rg * 8));
            acc2[nt] = __builtin_amdgcn_mfma_f32_16x16x32_bf16(a, b, acc2[nt], 0, 0, 0);
        }
    }

    // -------- epilogue: out = h2 @ W3^T + b3 --------
    float part[4] = {0.f, 0.f, 0.f, 0.f};
#pragma unroll
    for (int nt = 0; nt < 8; ++nt) {
        float bb = b2[nt * 16 + j];
        float w3 = W3[nt * 16 + j];
#pragma unroll
        for (int r = 0; r < 4; ++r)
            part[r] += __sinf(30.f * (acc2[nt][r] + bb)) * w3;
    }
#pragma unroll
    for (int off = 1; off < 16; off <<= 1) {
#pragma unroll
        for (int r = 0; r < 4; ++r) part[r] += __shfl_xor(part[r], off, 64);
    }
    if (j == 0) {
        float bb3 = b3[0];
#pragma unroll
        for (int r = 0; r < 4; ++r) {
            int p = pbase + rg * 4 + r;
            if (p < N) out[p] = part[r] + bb3;
        }
    }
}

extern "C" void kernel_launch(void* const* d_in, const int* in_sizes, int n_in,
                              void* d_out, int out_size, void* d_ws, size_t ws_size,
                              hipStream_t stream) {
    const float* coords = (const float*)d_in[0];
    const float* plane  = (const float*)d_in[1];
    const float* W1     = (const float*)d_in[4];
    const float* b1     = (const float*)d_in[5];
    const float* W2     = (const float*)d_in[6];
    const float* b2     = (const float*)d_in[7];
    const float* W3     = (const float*)d_in[8];
    const float* b3     = (const float*)d_in[9];
    float* out = (float*)d_out;
    int N = in_sizes[0] / 3;

    unsigned short* planeT = (unsigned short*)d_ws;                       // 16 MB
    unsigned short* W1b = (unsigned short*)((char*)d_ws + 16777216);      // 32 KB
    unsigned short* W2b = (unsigned short*)((char*)d_ws + 16777216 + 32768);

    k_transpose<<<dim3(HW * 8), dim3(256), 0, stream>>>(plane, planeT);
    k_wconv<<<dim3(128), dim3(256), 0, stream>>>(W1, W2, W1b, W2b);
    k_main<<<dim3((N + 31) / 32), dim3(128), 0, stream>>>(coords, planeT, W1b, W2b,
                                                          b1, b2, W3, b3, out, N);
}